// Round 17
// baseline (29.919 us; speedup 1.0000x reference)
//
#include <hip/hip_runtime.h>
#include <hip/hip_bf16.h>

#define NND 2000
#define KNB 16
#define CS 128
#define CZ 64
#define NE (NND*KNB)

typedef __attribute__((ext_vector_type(8))) short short8;
typedef __attribute__((ext_vector_type(4))) float f32x4;
typedef __attribute__((ext_vector_type(2))) unsigned int uint2v;
typedef __attribute__((ext_vector_type(4))) unsigned int uint4v;

// hardware bf16 convert (compiler emits v_cvt_pk_bf16_f32; RNE)
__device__ __forceinline__ unsigned int pk2(float a, float b) {
  __hip_bfloat162 h = __float22bfloat162_rn(make_float2(a, b));
  unsigned int u;
  __builtin_memcpy(&u, &h, 4);
  return u;
}
__device__ __forceinline__ unsigned short bfc(float f) {
  __hip_bfloat16 h = __float2bfloat16(f);
  unsigned short u;
  __builtin_memcpy(&u, &h, 2);
  return u;
}

__device__ __forceinline__ float fexp2(float x) {
#if __has_builtin(__builtin_amdgcn_exp2f)
  return __builtin_amdgcn_exp2f(x);
#else
  return __expf(0.6931471805599453f * x);
#endif
}

// ---------------------------------------------------------------------------
// Precompute (r12, unchanged):
//   blocks [0,500): E1 = exp(-(nf@wg1 + b_gate)), E2 = exp(-(nf@wg2)),
//     w_gate staged once per block into 64KB LDS.
//   block 500: wave0 bias2; wave1 wdbF; wave2 wedF; wave3 woF (bf16 frags).
// ---------------------------------------------------------------------------
__global__ __launch_bounds__(256) void precompute_kernel(
    const float* __restrict__ nf,
    const float* __restrict__ w_gate, const float* __restrict__ b_gate,
    const float* __restrict__ ln_b, const float* __restrict__ w_out,
    const float* __restrict__ b_out,
    const float* __restrict__ w_db, const float* __restrict__ w_edge,
    const float* __restrict__ ln_g,
    float* __restrict__ g1, float* __restrict__ g2, float* __restrict__ bias2,
    unsigned short* __restrict__ wdbF, unsigned short* __restrict__ wedF,
    unsigned short* __restrict__ woF)
{
  __shared__ float wl[2*CS][CZ];        // 64 KB: w_gate staged per block
  const int p = threadIdx.x;
  const int lane = p & 63;
  const int wv   = p >> 6;
  const int b    = blockIdx.x;
  if (b < NND/4) {
    #pragma unroll
    for (int t = 0; t < 16; ++t) {
      const int e = (p + 256*t) * 4;
      const f32x4 x = *(const f32x4*)&w_gate[e];
      *(f32x4*)&wl[e >> 6][e & 63] = x;
    }
    __syncthreads();

    const int v = b*4 + wv;
    const float* nrow = nf + v*CS;
    float a10=0.f,a11=0.f,a12=0.f,a13=0.f;
    float a20=0.f,a21=0.f,a22=0.f,a23=0.f;
    #pragma unroll
    for (int cc = 0; cc < CS; cc += 4) {
      const f32x4 x = *(const f32x4*)&nrow[cc];
      a10 = fmaf(x[0], wl[cc+0][lane], a10);
      a11 = fmaf(x[1], wl[cc+1][lane], a11);
      a12 = fmaf(x[2], wl[cc+2][lane], a12);
      a13 = fmaf(x[3], wl[cc+3][lane], a13);
      a20 = fmaf(x[0], wl[CS+cc+0][lane], a20);
      a21 = fmaf(x[1], wl[CS+cc+1][lane], a21);
      a22 = fmaf(x[2], wl[CS+cc+2][lane], a22);
      a23 = fmaf(x[3], wl[CS+cc+3][lane], a23);
    }
    const float a1 = b_gate[lane] + ((a10+a11)+(a12+a13));
    const float a2 = (a20+a21)+(a22+a23);
    g1[v*CZ + lane] = fexp2(a1 * -1.4426950408889634f);
    g2[v*CZ + lane] = fexp2(a2 * -1.4426950408889634f);
  } else {
    if (wv == 0) {
      float a = b_out[lane];
      #pragma unroll
      for (int cc = 0; cc < CZ; ++cc)
        a = fmaf(ln_b[cc], w_out[cc*CZ + lane], a);
      bias2[lane] = a;
    } else if (wv == 1) {
      for (int e = lane; e < 4096; e += 64) {
        const int entry = e >> 3, t = e & 7;
        const int l2 = entry & 63, sn = entry >> 6;
        const int s = sn >> 2, nt = sn & 3;
        const int q2 = l2 >> 4, c2 = l2 & 15;
        wdbF[e] = bfc(w_db[(32*s + 8*q2 + t)*CZ + 16*nt + c2]);
      }
    } else if (wv == 2) {
      for (int e = lane; e < 4096; e += 64) {
        const int entry = e >> 3, t = e & 7;
        const int p2 = entry & 255, s = entry >> 8;
        const int q2 = (p2 >> 4) & 3, c2 = p2 & 15;
        wedF[e] = bfc(w_edge[(32*s + 8*q2 + t)*CZ + 16*(p2 >> 6) + c2]);
      }
    } else {
      for (int e = lane; e < 4096; e += 64) {
        const int entry = e >> 3, t = e & 7;
        const int p2 = entry & 255, s = entry >> 8;
        const int q2 = (p2 >> 4) & 3, c2 = p2 & 15;
        const int k = 32*s + 8*q2 + t;
        woF[e] = bfc(w_out[k*CZ + 16*(p2 >> 6) + c2] * ln_g[k]);
      }
    }
  }
}

// ---------------------------------------------------------------------------
// Fused main kernel: r16 verbatim (29.41us), ONE change: the gate's four
// reciprocals per (m,nt) quad are computed via Montgomery batch inversion
// (1 rcp + 9 mul instead of 4 rcp). d_r = 1+E1_r*E2_m <= ~100 (logit scale
// ~0.6 sigma) -> P <= 1e8, no overflow; error ~4 ulp on a (0,1) gate.
// ---------------------------------------------------------------------------
__global__ __launch_bounds__(256, 4) void fused_main_kernel(
    const float* __restrict__ trans, const int* __restrict__ eidx,
    const float* __restrict__ g1, const float* __restrict__ g2,
    const float* __restrict__ ef, const float* __restrict__ b_edge,
    const float* __restrict__ b_db, const float* __restrict__ bias2,
    const unsigned short* __restrict__ wdbF,
    const unsigned short* __restrict__ wedF,
    const unsigned short* __restrict__ woF,
    float* __restrict__ out)
{
  __shared__ float G1l[KNB][68];
  __shared__ float G2l[KNB][68];
  __shared__ float kfl[KNB][68];
  __shared__ unsigned short xh[KNB][72];     // xhat bf16 (also ef-tile buffer)

  const int n = blockIdx.x;
  const int p = threadIdx.x;
  const int w = p >> 6;
  const int l = p & 63;
  const int q = l >> 4;
  const int c = l & 15;
  const int r16 = p >> 4, c4 = (p & 15) * 4;

  // ---- front-loaded global traffic --------------------------------------
  const int sr = eidx[n*KNB + r16];
  const int sc = eidx[n*KNB + c];
  int sj[4];
  #pragma unroll
  for (int m = 0; m < 4; ++m) sj[m] = eidx[n*KNB + 4*w + m];

  const f32x4 g1row = *(const f32x4*)&g1[sr*CZ + c4];
  const f32x4 g2row = *(const f32x4*)&g2[sr*CZ + c4];
  const f32x4 efrow = *(const f32x4*)&ef[(n*KNB + r16)*CZ + c4];

  const float tc0 = trans[sc*3+0], tc1 = trans[sc*3+1], tc2 = trans[sc*3+2];
  float tj[4][3];
  #pragma unroll
  for (int m = 0; m < 4; ++m) {
    tj[m][0] = trans[sj[m]*3+0];
    tj[m][1] = trans[sj[m]*3+1];
    tj[m][2] = trans[sj[m]*3+2];
  }

  short8 wed[2];
  #pragma unroll
  for (int s = 0; s < 2; ++s)
    wed[s] = *(const short8*)&wedF[(s*256 + p)*8];
  short8 bcur[2];
  #pragma unroll
  for (int s = 0; s < 2; ++s)
    bcur[s] = *(const short8*)&wdbF[(s*4*64 + l)*8];

  const float be = b_edge[16*w + c];
  const float bo = bias2[16*w + c];
  float bdb[4];
  #pragma unroll
  for (int nt = 0; nt < 4; ++nt) bdb[nt] = b_db[16*nt + c];

  // ---- register-only compute while loads land ---------------------------
  const float STEP = 1.2201878439258035f;
  float dsc[4];
  #pragma unroll
  for (int m = 0; m < 4; ++m) {
    const float dx = tc0 - tj[m][0] + 1e-8f;
    const float dy = tc1 - tj[m][1] + 1e-8f;
    const float dz = tc2 - tj[m][2] + 1e-8f;
    dsc[m] = sqrtf(fmaf(dx,dx, fmaf(dy,dy, dz*dz))) * 3.8435917081166394f;
  }
  const float qoff = (float)(8*q) * STEP;

  // rbf A-frags: center-start geometric recurrence (r16, verified)
  const float D32 = fexp2(-2.0f * STEP * STEP);
  const float S2  = STEP * STEP;
  short8 af[2][4];
  #pragma unroll
  for (int s = 0; s < 2; ++s) {
    const float soff = qoff + (float)(32*s) * STEP;
    #pragma unroll
    for (int m = 0; m < 4; ++m) {
      const float bse = dsc[m] - soff;
      const float u = fmaxf(-40.0f, fminf(40.0f, bse));
      const float wc = u - 4.0f*STEP;                // center-relative
      const float v4 = fexp2(-wc*wc);
      float gu = fexp2(fmaf( 2.0f*STEP, wc, -S2));
      float gd = fexp2(fmaf(-2.0f*STEP, wc, -S2));
      float r = v4;
      r *= gu; const float v5 = r; gu *= D32;
      r *= gu; const float v6 = r; gu *= D32;
      r *= gu; const float v7 = r;
      r = v4;
      r *= gd; const float v3 = r; gd *= D32;
      r *= gd; const float v2 = r; gd *= D32;
      r *= gd; const float v1 = r; gd *= D32;
      r *= gd; const float v0 = r;
      uint4v u4;
      u4[0] = pk2(v0, v1);
      u4[1] = pk2(v2, v3);
      u4[2] = pk2(v4, v5);
      u4[3] = pk2(v6, v7);
      short8 v;
      __builtin_memcpy(&v, &u4, 16);
      af[s][m] = v;
    }
  }

  { // stage ef tile bf16 (into xh) + G rows (register -> LDS)
    uint2v pk;
    pk[0] = pk2(efrow[0], efrow[1]);
    pk[1] = pk2(efrow[2], efrow[3]);
    *(uint2v*)&xh[r16][c4] = pk;
    *(f32x4*)&G1l[r16][c4] = g1row;
    *(f32x4*)&G2l[r16][c4] = g2row;
  }
  __syncthreads();   // b1: ef tile (in xh), G1l, G2l visible

  { // MFMA0: kf tile; wave w owns cols 16w..16w+15
    f32x4 ak = {};
    #pragma unroll
    for (int s = 0; s < 2; ++s) {
      const short8 a0 = *(const short8*)&xh[c][q*8 + 32*s];
      ak = __builtin_amdgcn_mfma_f32_16x16x32_bf16(a0, wed[s], ak, 0, 0, 0);
    }
    #pragma unroll
    for (int r = 0; r < 4; ++r)
      kfl[4*q + r][16*w + c] = ak[r] + be;
  }
  __syncthreads();   // b2: kfl visible (xh free again)

  // ---- per-nt fused MFMA1 + gate (batch-rcp) + i-reduce -----------------
  float upd[4][4];   // [m][nt]
  #pragma unroll
  for (int nt = 0; nt < 4; ++nt) {
    short8 bnext[2];
    if (nt < 3) {
      #pragma unroll
      for (int s = 0; s < 2; ++s)
        bnext[s] = *(const short8*)&wdbF[((s*4 + nt+1)*64 + l)*8];
    }
    float e1v[4], kfv[4];
    #pragma unroll
    for (int r = 0; r < 4; ++r) {
      e1v[r] = G1l[4*q + r][16*nt + c];   // E1[i,h]
      kfv[r] = kfl[4*q + r][16*nt + c];
    }
    const float bdbn = bdb[nt];
    f32x4 acc[4];
    #pragma unroll
    for (int m = 0; m < 4; ++m) acc[m] = (f32x4){bdbn, bdbn, bdbn, bdbn};
    #pragma unroll
    for (int s = 0; s < 2; ++s)
      #pragma unroll
      for (int m = 0; m < 4; ++m)
        acc[m] = __builtin_amdgcn_mfma_f32_16x16x32_bf16(af[s][m], bcur[s], acc[m], 0, 0, 0);

    #pragma unroll
    for (int m = 0; m < 4; ++m) {
      const float e2m = G2l[4*w + m][16*nt + c];   // E2[j,h]
      // batch inversion: 1 rcp for the 4 sigmoid denominators
      const float d0 = fmaf(e1v[0], e2m, 1.0f);
      const float d1 = fmaf(e1v[1], e2m, 1.0f);
      const float d2 = fmaf(e1v[2], e2m, 1.0f);
      const float d3 = fmaf(e1v[3], e2m, 1.0f);
      const float p01  = d0*d1;
      const float p012 = p01*d2;
      const float ip   = __builtin_amdgcn_rcpf(p012*d3);
      const float i3   = ip * p012;
      const float ipp  = ip * d3;     // 1/(d0 d1 d2)
      const float i2   = ipp * p01;
      const float ipq  = ipp * d2;    // 1/(d0 d1)
      const float i1   = ipq * d0;
      const float i0   = ipq * d1;
      float ss;
      ss =      (acc[m][0] * i0) * kfv[0];
      ss = fmaf  (acc[m][1] * i1,  kfv[1], ss);
      ss = fmaf  (acc[m][2] * i2,  kfv[2], ss);
      ss = fmaf  (acc[m][3] * i3,  kfv[3], ss);
      ss += __shfl_xor(ss, 16);
      ss += __shfl_xor(ss, 32);
      upd[m][nt] = ss;
    }
    if (nt < 3) { bcur[0] = bnext[0]; bcur[1] = bnext[1]; }
  }

  // proj B-frags (hide under LN)
  short8 wb[2];
  #pragma unroll
  for (int s = 0; s < 2; ++s)
    wb[s] = *(const short8*)&woF[(s*256 + p)*8];

  // ---- LayerNorm: q-group q owns row j = 4w+q ---------------------------
  {
    float v[4];
    #pragma unroll
    for (int nt = 0; nt < 4; ++nt)
      v[nt] = (q == 0) ? upd[0][nt] : (q == 1) ? upd[1][nt]
            : (q == 2) ? upd[2][nt] : upd[3][nt];
    float s1 = (v[0] + v[1]) + (v[2] + v[3]);
    float s2 = fmaf(v[0],v[0], fmaf(v[1],v[1], fmaf(v[2],v[2], v[3]*v[3])));
    #pragma unroll
    for (int mk = 1; mk <= 8; mk <<= 1) {
      s1 += __shfl_xor(s1, mk);
      s2 += __shfl_xor(s2, mk);
    }
    const float mean = s1 * 0.015625f;
    const float var  = fmaf(s2, 0.015625f, -mean*mean);
    const float rstd = rsqrtf(var + 1e-5f);
    #pragma unroll
    for (int nt = 0; nt < 4; ++nt)
      xh[4*w + q][16*nt + c] = bfc((v[nt] - mean) * rstd);
  }
  __syncthreads();   // b3: xh visible

  // ---- MFMA2: out = xhat @ (ln_g*w_out) + bias2 -------------------------
  f32x4 acc2 = {};
  #pragma unroll
  for (int s = 0; s < 2; ++s) {
    const short8 a2f = *(const short8*)&xh[c][q*8 + 32*s];
    acc2 = __builtin_amdgcn_mfma_f32_16x16x32_bf16(a2f, wb[s], acc2, 0, 0, 0);
  }
  #pragma unroll
  for (int r = 0; r < 4; ++r)
    out[(n*KNB + 4*q + r)*CZ + 16*w + c] = acc2[r] + bo;
}

extern "C" void kernel_launch(void* const* d_in, const int* in_sizes, int n_in,
                              void* d_out, int out_size, void* d_ws, size_t ws_size,
                              hipStream_t stream)
{
  const float* nf     = (const float*)d_in[0];
  const float* trans  = (const float*)d_in[1];
  const float* ef     = (const float*)d_in[2];
  const int*   eidx   = (const int*)d_in[3];
  const float* w_gate = (const float*)d_in[4];
  const float* b_gate = (const float*)d_in[5];
  const float* w_db   = (const float*)d_in[6];
  const float* b_db   = (const float*)d_in[7];
  const float* w_edge = (const float*)d_in[8];
  const float* b_edge = (const float*)d_in[9];
  const float* ln_g   = (const float*)d_in[10];
  const float* ln_b   = (const float*)d_in[11];
  const float* w_out  = (const float*)d_in[12];
  const float* b_out  = (const float*)d_in[13];
  float* out = (float*)d_out;

  float* g1    = (float*)d_ws;                            // E1 [2000][64] f32
  float* g2    = g1 + NND*CZ;                             // E2 [2000][64] f32
  float* bias2 = g2 + NND*CZ;                             // [64] f32
  unsigned short* wdbF = (unsigned short*)(bias2 + CZ);   // 4096 bf16
  unsigned short* wedF = wdbF + 4096;                     // 4096 bf16
  unsigned short* woF  = wedF + 4096;                     // 4096 bf16

  precompute_kernel<<<NND/4 + 1, 256, 0, stream>>>(
      nf, w_gate, b_gate, ln_b, w_out, b_out, w_db, w_edge, ln_g,
      g1, g2, bias2, wdbF, wedF, woF);
  fused_main_kernel<<<NND, 256, 0, stream>>>(
      trans, eidx, g1, g2, ef, b_edge, b_db, bias2,
      wdbF, wedF, woF, out);
}

// Round 18
// 29.423 us; speedup vs baseline: 1.0169x; 1.0169x over previous
//
#include <hip/hip_runtime.h>
#include <hip/hip_bf16.h>

#define NND 2000
#define KNB 16
#define CS 128
#define CZ 64
#define NE (NND*KNB)

typedef __attribute__((ext_vector_type(8))) short short8;
typedef __attribute__((ext_vector_type(4))) float f32x4;
typedef __attribute__((ext_vector_type(2))) unsigned int uint2v;
typedef __attribute__((ext_vector_type(4))) unsigned int uint4v;

// hardware bf16 convert (compiler emits v_cvt_pk_bf16_f32; RNE)
__device__ __forceinline__ unsigned int pk2(float a, float b) {
  __hip_bfloat162 h = __float22bfloat162_rn(make_float2(a, b));
  unsigned int u;
  __builtin_memcpy(&u, &h, 4);
  return u;
}
__device__ __forceinline__ unsigned short bfc(float f) {
  __hip_bfloat16 h = __float2bfloat16(f);
  unsigned short u;
  __builtin_memcpy(&u, &h, 2);
  return u;
}

__device__ __forceinline__ float fexp2(float x) {
#if __has_builtin(__builtin_amdgcn_exp2f)
  return __builtin_amdgcn_exp2f(x);
#else
  return __expf(0.6931471805599453f * x);
#endif
}

// ---------------------------------------------------------------------------
// Precompute:
//   blocks [0,500): E1 = exp(-(nf@wg1 + b_gate)), E2 = exp(-(nf@wg2)),
//     w_gate staged once per block into 64KB LDS.
//   block 500: wave0 bias2; wave1 wdbF; wave2 wedF; wave3 woF (bf16 frags).
// ---------------------------------------------------------------------------
__global__ __launch_bounds__(256) void precompute_kernel(
    const float* __restrict__ nf,
    const float* __restrict__ w_gate, const float* __restrict__ b_gate,
    const float* __restrict__ ln_b, const float* __restrict__ w_out,
    const float* __restrict__ b_out,
    const float* __restrict__ w_db, const float* __restrict__ w_edge,
    const float* __restrict__ ln_g,
    float* __restrict__ g1, float* __restrict__ g2, float* __restrict__ bias2,
    unsigned short* __restrict__ wdbF, unsigned short* __restrict__ wedF,
    unsigned short* __restrict__ woF)
{
  __shared__ float wl[2*CS][CZ];        // 64 KB: w_gate staged per block
  const int p = threadIdx.x;
  const int lane = p & 63;
  const int wv   = p >> 6;
  const int b    = blockIdx.x;
  if (b < NND/4) {
    #pragma unroll
    for (int t = 0; t < 16; ++t) {
      const int e = (p + 256*t) * 4;
      const f32x4 x = *(const f32x4*)&w_gate[e];
      *(f32x4*)&wl[e >> 6][e & 63] = x;
    }
    __syncthreads();

    const int v = b*4 + wv;
    const float* nrow = nf + v*CS;
    float a10=0.f,a11=0.f,a12=0.f,a13=0.f;
    float a20=0.f,a21=0.f,a22=0.f,a23=0.f;
    #pragma unroll
    for (int cc = 0; cc < CS; cc += 4) {
      const f32x4 x = *(const f32x4*)&nrow[cc];
      a10 = fmaf(x[0], wl[cc+0][lane], a10);
      a11 = fmaf(x[1], wl[cc+1][lane], a11);
      a12 = fmaf(x[2], wl[cc+2][lane], a12);
      a13 = fmaf(x[3], wl[cc+3][lane], a13);
      a20 = fmaf(x[0], wl[CS+cc+0][lane], a20);
      a21 = fmaf(x[1], wl[CS+cc+1][lane], a21);
      a22 = fmaf(x[2], wl[CS+cc+2][lane], a22);
      a23 = fmaf(x[3], wl[CS+cc+3][lane], a23);
    }
    const float a1 = b_gate[lane] + ((a10+a11)+(a12+a13));
    const float a2 = (a20+a21)+(a22+a23);
    g1[v*CZ + lane] = fexp2(a1 * -1.4426950408889634f);
    g2[v*CZ + lane] = fexp2(a2 * -1.4426950408889634f);
  } else {
    if (wv == 0) {
      float a = b_out[lane];
      #pragma unroll
      for (int cc = 0; cc < CZ; ++cc)
        a = fmaf(ln_b[cc], w_out[cc*CZ + lane], a);
      bias2[lane] = a;
    } else if (wv == 1) {
      for (int e = lane; e < 4096; e += 64) {
        const int entry = e >> 3, t = e & 7;
        const int l2 = entry & 63, sn = entry >> 6;
        const int s = sn >> 2, nt = sn & 3;
        const int q2 = l2 >> 4, c2 = l2 & 15;
        wdbF[e] = bfc(w_db[(32*s + 8*q2 + t)*CZ + 16*nt + c2]);
      }
    } else if (wv == 2) {
      for (int e = lane; e < 4096; e += 64) {
        const int entry = e >> 3, t = e & 7;
        const int p2 = entry & 255, s = entry >> 8;
        const int q2 = (p2 >> 4) & 3, c2 = p2 & 15;
        wedF[e] = bfc(w_edge[(32*s + 8*q2 + t)*CZ + 16*(p2 >> 6) + c2]);
      }
    } else {
      for (int e = lane; e < 4096; e += 64) {
        const int entry = e >> 3, t = e & 7;
        const int p2 = entry & 255, s = entry >> 8;
        const int q2 = (p2 >> 4) & 3, c2 = p2 & 15;
        const int k = 32*s + 8*q2 + t;
        woF[e] = bfc(w_out[k*CZ + 16*(p2 >> 6) + c2] * ln_g[k]);
      }
    }
  }
}

// ---------------------------------------------------------------------------
// Fused main kernel (r16, best: 29.41us): r12 structure + center-start
// geometric recurrence for the rbf A-frags (3 exp2 + ~18 VALU per 8-group).
// Chain starts at t=4 (chunk center): r4 = exp2(-w^2), w = u-4S; up-ratio
// gu0 = exp2(2Sw - S^2), down-ratio gd0 = exp2(-2Sw - S^2), both *= D =
// exp2(-2S^2) per step. Start value underflows only where all true chunk
// values < 2^-40 -> abs error <= 1e-12. Gate = rcp(1 + E1*E2) (4 pipelined
// rcp per quad -- batch inversion regressed, r17).
// ---------------------------------------------------------------------------
__global__ __launch_bounds__(256, 4) void fused_main_kernel(
    const float* __restrict__ trans, const int* __restrict__ eidx,
    const float* __restrict__ g1, const float* __restrict__ g2,
    const float* __restrict__ ef, const float* __restrict__ b_edge,
    const float* __restrict__ b_db, const float* __restrict__ bias2,
    const unsigned short* __restrict__ wdbF,
    const unsigned short* __restrict__ wedF,
    const unsigned short* __restrict__ woF,
    float* __restrict__ out)
{
  __shared__ float G1l[KNB][68];
  __shared__ float G2l[KNB][68];
  __shared__ float kfl[KNB][68];
  __shared__ unsigned short xh[KNB][72];     // xhat bf16 (also ef-tile buffer)

  const int n = blockIdx.x;
  const int p = threadIdx.x;
  const int w = p >> 6;
  const int l = p & 63;
  const int q = l >> 4;
  const int c = l & 15;
  const int r16 = p >> 4, c4 = (p & 15) * 4;

  // ---- front-loaded global traffic --------------------------------------
  const int sr = eidx[n*KNB + r16];
  const int sc = eidx[n*KNB + c];
  int sj[4];
  #pragma unroll
  for (int m = 0; m < 4; ++m) sj[m] = eidx[n*KNB + 4*w + m];

  const f32x4 g1row = *(const f32x4*)&g1[sr*CZ + c4];
  const f32x4 g2row = *(const f32x4*)&g2[sr*CZ + c4];
  const f32x4 efrow = *(const f32x4*)&ef[(n*KNB + r16)*CZ + c4];

  const float tc0 = trans[sc*3+0], tc1 = trans[sc*3+1], tc2 = trans[sc*3+2];
  float tj[4][3];
  #pragma unroll
  for (int m = 0; m < 4; ++m) {
    tj[m][0] = trans[sj[m]*3+0];
    tj[m][1] = trans[sj[m]*3+1];
    tj[m][2] = trans[sj[m]*3+2];
  }

  short8 wed[2];
  #pragma unroll
  for (int s = 0; s < 2; ++s)
    wed[s] = *(const short8*)&wedF[(s*256 + p)*8];
  short8 bcur[2];
  #pragma unroll
  for (int s = 0; s < 2; ++s)
    bcur[s] = *(const short8*)&wdbF[(s*4*64 + l)*8];

  const float be = b_edge[16*w + c];
  const float bo = bias2[16*w + c];
  float bdb[4];
  #pragma unroll
  for (int nt = 0; nt < 4; ++nt) bdb[nt] = b_db[16*nt + c];

  // ---- register-only compute while loads land ---------------------------
  const float STEP = 1.2201878439258035f;
  float dsc[4];
  #pragma unroll
  for (int m = 0; m < 4; ++m) {
    const float dx = tc0 - tj[m][0] + 1e-8f;
    const float dy = tc1 - tj[m][1] + 1e-8f;
    const float dz = tc2 - tj[m][2] + 1e-8f;
    dsc[m] = sqrtf(fmaf(dx,dx, fmaf(dy,dy, dz*dz))) * 3.8435917081166394f;
  }
  const float qoff = (float)(8*q) * STEP;

  // rbf A-frags: center-start geometric recurrence
  const float D32 = fexp2(-2.0f * STEP * STEP);
  const float S2  = STEP * STEP;
  short8 af[2][4];
  #pragma unroll
  for (int s = 0; s < 2; ++s) {
    const float soff = qoff + (float)(32*s) * STEP;
    #pragma unroll
    for (int m = 0; m < 4; ++m) {
      const float bse = dsc[m] - soff;
      const float u = fmaxf(-40.0f, fminf(40.0f, bse));
      const float wc = u - 4.0f*STEP;                // center-relative
      const float v4 = fexp2(-wc*wc);
      float gu = fexp2(fmaf( 2.0f*STEP, wc, -S2));
      float gd = fexp2(fmaf(-2.0f*STEP, wc, -S2));
      float r = v4;
      r *= gu; const float v5 = r; gu *= D32;
      r *= gu; const float v6 = r; gu *= D32;
      r *= gu; const float v7 = r;
      r = v4;
      r *= gd; const float v3 = r; gd *= D32;
      r *= gd; const float v2 = r; gd *= D32;
      r *= gd; const float v1 = r; gd *= D32;
      r *= gd; const float v0 = r;
      uint4v u4;
      u4[0] = pk2(v0, v1);
      u4[1] = pk2(v2, v3);
      u4[2] = pk2(v4, v5);
      u4[3] = pk2(v6, v7);
      short8 v;
      __builtin_memcpy(&v, &u4, 16);
      af[s][m] = v;
    }
  }

  { // stage ef tile bf16 (into xh) + G rows (register -> LDS)
    uint2v pk;
    pk[0] = pk2(efrow[0], efrow[1]);
    pk[1] = pk2(efrow[2], efrow[3]);
    *(uint2v*)&xh[r16][c4] = pk;
    *(f32x4*)&G1l[r16][c4] = g1row;
    *(f32x4*)&G2l[r16][c4] = g2row;
  }
  __syncthreads();   // b1: ef tile (in xh), G1l, G2l visible

  { // MFMA0: kf tile; wave w owns cols 16w..16w+15
    f32x4 ak = {};
    #pragma unroll
    for (int s = 0; s < 2; ++s) {
      const short8 a0 = *(const short8*)&xh[c][q*8 + 32*s];
      ak = __builtin_amdgcn_mfma_f32_16x16x32_bf16(a0, wed[s], ak, 0, 0, 0);
    }
    #pragma unroll
    for (int r = 0; r < 4; ++r)
      kfl[4*q + r][16*w + c] = ak[r] + be;
  }
  __syncthreads();   // b2: kfl visible (xh free again)

  // ---- per-nt fused MFMA1 + gate + i-reduce -----------------------------
  float upd[4][4];   // [m][nt]
  #pragma unroll
  for (int nt = 0; nt < 4; ++nt) {
    short8 bnext[2];
    if (nt < 3) {
      #pragma unroll
      for (int s = 0; s < 2; ++s)
        bnext[s] = *(const short8*)&wdbF[((s*4 + nt+1)*64 + l)*8];
    }
    float e1v[4], kfv[4];
    #pragma unroll
    for (int r = 0; r < 4; ++r) {
      e1v[r] = G1l[4*q + r][16*nt + c];   // E1[i,h]
      kfv[r] = kfl[4*q + r][16*nt + c];
    }
    const float bdbn = bdb[nt];
    f32x4 acc[4];
    #pragma unroll
    for (int m = 0; m < 4; ++m) acc[m] = (f32x4){bdbn, bdbn, bdbn, bdbn};
    #pragma unroll
    for (int s = 0; s < 2; ++s)
      #pragma unroll
      for (int m = 0; m < 4; ++m)
        acc[m] = __builtin_amdgcn_mfma_f32_16x16x32_bf16(af[s][m], bcur[s], acc[m], 0, 0, 0);

    #pragma unroll
    for (int m = 0; m < 4; ++m) {
      const float e2m = G2l[4*w + m][16*nt + c];   // E2[j,h]
      float ss = 0.f;
      #pragma unroll
      for (int r = 0; r < 4; ++r) {
        const float gate = __builtin_amdgcn_rcpf(fmaf(e1v[r], e2m, 1.0f));
        ss = fmaf(gate * acc[m][r], kfv[r], ss);
      }
      ss += __shfl_xor(ss, 16);
      ss += __shfl_xor(ss, 32);
      upd[m][nt] = ss;
    }
    if (nt < 3) { bcur[0] = bnext[0]; bcur[1] = bnext[1]; }
  }

  // proj B-frags (hide under LN)
  short8 wb[2];
  #pragma unroll
  for (int s = 0; s < 2; ++s)
    wb[s] = *(const short8*)&woF[(s*256 + p)*8];

  // ---- LayerNorm: q-group q owns row j = 4w+q ---------------------------
  {
    float v[4];
    #pragma unroll
    for (int nt = 0; nt < 4; ++nt)
      v[nt] = (q == 0) ? upd[0][nt] : (q == 1) ? upd[1][nt]
            : (q == 2) ? upd[2][nt] : upd[3][nt];
    float s1 = (v[0] + v[1]) + (v[2] + v[3]);
    float s2 = fmaf(v[0],v[0], fmaf(v[1],v[1], fmaf(v[2],v[2], v[3]*v[3])));
    #pragma unroll
    for (int mk = 1; mk <= 8; mk <<= 1) {
      s1 += __shfl_xor(s1, mk);
      s2 += __shfl_xor(s2, mk);
    }
    const float mean = s1 * 0.015625f;
    const float var  = fmaf(s2, 0.015625f, -mean*mean);
    const float rstd = rsqrtf(var + 1e-5f);
    #pragma unroll
    for (int nt = 0; nt < 4; ++nt)
      xh[4*w + q][16*nt + c] = bfc((v[nt] - mean) * rstd);
  }
  __syncthreads();   // b3: xh visible

  // ---- MFMA2: out = xhat @ (ln_g*w_out) + bias2 -------------------------
  f32x4 acc2 = {};
  #pragma unroll
  for (int s = 0; s < 2; ++s) {
    const short8 a2f = *(const short8*)&xh[c][q*8 + 32*s];
    acc2 = __builtin_amdgcn_mfma_f32_16x16x32_bf16(a2f, wb[s], acc2, 0, 0, 0);
  }
  #pragma unroll
  for (int r = 0; r < 4; ++r)
    out[(n*KNB + 4*q + r)*CZ + 16*w + c] = acc2[r] + bo;
}

extern "C" void kernel_launch(void* const* d_in, const int* in_sizes, int n_in,
                              void* d_out, int out_size, void* d_ws, size_t ws_size,
                              hipStream_t stream)
{
  const float* nf     = (const float*)d_in[0];
  const float* trans  = (const float*)d_in[1];
  const float* ef     = (const float*)d_in[2];
  const int*   eidx   = (const int*)d_in[3];
  const float* w_gate = (const float*)d_in[4];
  const float* b_gate = (const float*)d_in[5];
  const float* w_db   = (const float*)d_in[6];
  const float* b_db   = (const float*)d_in[7];
  const float* w_edge = (const float*)d_in[8];
  const float* b_edge = (const float*)d_in[9];
  const float* ln_g   = (const float*)d_in[10];
  const float* ln_b   = (const float*)d_in[11];
  const float* w_out  = (const float*)d_in[12];
  const float* b_out  = (const float*)d_in[13];
  float* out = (float*)d_out;

  float* g1    = (float*)d_ws;                            // E1 [2000][64] f32
  float* g2    = g1 + NND*CZ;                             // E2 [2000][64] f32
  float* bias2 = g2 + NND*CZ;                             // [64] f32
  unsigned short* wdbF = (unsigned short*)(bias2 + CZ);   // 4096 bf16
  unsigned short* wedF = wdbF + 4096;                     // 4096 bf16
  unsigned short* woF  = wedF + 4096;                     // 4096 bf16

  precompute_kernel<<<NND/4 + 1, 256, 0, stream>>>(
      nf, w_gate, b_gate, ln_b, w_out, b_out, w_db, w_edge, ln_g,
      g1, g2, bias2, wdbF, wedF, woF);
  fused_main_kernel<<<NND, 256, 0, stream>>>(
      trans, eidx, g1, g2, ef, b_edge, b_db, bias2,
      wdbF, wedF, woF, out);
}